// Round 2
// baseline (599.671 us; speedup 1.0000x reference)
//
#include <hip/hip_runtime.h>
#include <cstdint>
#include <cstddef>

#define D_NUM 4
#define N_ES  2
#define N_SH  4
#define DIN   512
#define HDIM  256
#define BB    16384
#define NMAT  12        // 8 spec (n*2+e) + 4 shared
#define NGATE 36        // 4*6 domain gates + 12 shared gates

typedef __bf16 bf16x8 __attribute__((ext_vector_type(8)));
typedef float  f32x4  __attribute__((ext_vector_type(4)));

__device__ __forceinline__ unsigned short f2bf(float f) {
    union { float f; unsigned u; } v; v.f = f;
    unsigned u = v.u;
    unsigned r = (u + 0x7FFFu + ((u >> 16) & 1u)) >> 16;   // RNE
    return (unsigned short)r;
}

__device__ __forceinline__ void async16(void* l, const void* g) {
    __builtin_amdgcn_global_load_lds(
        (const __attribute__((address_space(1))) void*)g,
        (__attribute__((address_space(3))) void*)l,
        16, 0, 0);
}

template <int N>
__device__ __forceinline__ void softmaxN(float* z) {
    float m = z[0];
    #pragma unroll
    for (int i = 1; i < N; ++i) m = fmaxf(m, z[i]);
    float s = 0.f;
    #pragma unroll
    for (int i = 0; i < N; ++i) { z[i] = __expf(z[i] - m); s += z[i]; }
    float r = 1.f / s;
    #pragma unroll
    for (int i = 0; i < N; ++i) z[i] *= r;
}

// ---------------------------------------------------------------------------
// Kernel W: convert + transpose weights to bf16 WT[mat][h][k] via LDS tiles.
// Coalesced reads (lanes stride h) and coalesced-ish writes (lanes stride k).
// ---------------------------------------------------------------------------
__global__ __launch_bounds__(256) void k_wconv(
    const float* __restrict__ Wspec,   // (4,2,512,256) = (mat,k,h)
    const float* __restrict__ Wsh,     // (4,512,256)
    unsigned short* __restrict__ WT)   // (12,256,512) = (mat,h,k)
{
    __shared__ unsigned short t[64][65];          // +1 pad breaks transpose conflicts
    const int mat = blockIdx.z;
    const int k0  = blockIdx.x * 64;
    const int h0  = blockIdx.y * 64;
    const float* src = (mat < 8) ? (Wspec + (size_t)mat * DIN * HDIM)
                                 : (Wsh   + (size_t)(mat - 8) * DIN * HDIM);
    #pragma unroll
    for (int i = 0; i < 16; ++i) {
        int idx = i * 256 + threadIdx.x;
        int r = idx >> 6, c = idx & 63;           // r = k, c = h (coalesced in h)
        t[r][c] = f2bf(src[(size_t)(k0 + r) * HDIM + h0 + c]);
    }
    __syncthreads();
    #pragma unroll
    for (int i = 0; i < 16; ++i) {
        int idx = i * 256 + threadIdx.x;
        int r = idx >> 6, c = idx & 63;           // r = h, c = k (coalesced in k)
        WT[(size_t)mat * HDIM * DIN + (size_t)(h0 + r) * DIN + k0 + c] = t[c][r];
    }
}

// ---------------------------------------------------------------------------
// Kernel A: x f32 -> bf16 copy + gate probabilities (double softmax + mask).
// One wave per row. Planes processed sequentially; gate weights loaded as
// float4 half-chunks to keep live VGPRs ~100 (round-1 spilled at 48 VGPRs,
// +145 MB scratch traffic).
// ---------------------------------------------------------------------------
__global__ __launch_bounds__(256, 4) void k_prep(
    const float* __restrict__ x,        // (5,B,512)
    const int*   __restrict__ simdom,   // (4,2)
    const float* __restrict__ Wg,       // (4,512,6)
    const float* __restrict__ bg,       // (4,6)
    const float* __restrict__ Wgs,      // (512,12)
    const float* __restrict__ bgs,      // (12)
    unsigned short* __restrict__ xbf,   // (5,B,512)
    float* __restrict__ gates)          // (B,36)
{
    const int wave = threadIdx.x >> 6;
    const int lane = threadIdx.x & 63;
    const int row  = blockIdx.x * 4 + wave;
    const int k0   = lane * 8;

    float acc[NGATE];
    #pragma unroll
    for (int i = 0; i < NGATE; ++i) acc[i] = 0.f;

    #pragma unroll
    for (int m = 0; m < 5; ++m) {
        const float* xp = x + ((size_t)m * BB + row) * DIN + k0;
        float4 a = ((const float4*)xp)[0], b = ((const float4*)xp)[1];
        float xv[8];
        xv[0]=a.x; xv[1]=a.y; xv[2]=a.z; xv[3]=a.w;
        xv[4]=b.x; xv[5]=b.y; xv[6]=b.z; xv[7]=b.w;
        union { unsigned short us[8]; uint4 v; } pk;
        #pragma unroll
        for (int j = 0; j < 8; ++j) pk.us[j] = f2bf(xv[j]);
        *(uint4*)(xbf + ((size_t)m * BB + row) * DIN + k0) = pk.v;

        if (m < 4) {
            #pragma unroll
            for (int half = 0; half < 2; ++half) {
                const float4* wp = (const float4*)(Wg + ((size_t)m * DIN + k0 + half * 4) * 6);
                float wf[24];
                #pragma unroll
                for (int tchunk = 0; tchunk < 6; ++tchunk)
                    ((float4*)wf)[tchunk] = wp[tchunk];
                #pragma unroll
                for (int j2 = 0; j2 < 4; ++j2)
                    #pragma unroll
                    for (int e = 0; e < 6; ++e)
                        acc[m * 6 + e] += xv[half * 4 + j2] * wf[j2 * 6 + e];
            }
        } else {
            #pragma unroll
            for (int half = 0; half < 2; ++half) {
                const float4* wp = (const float4*)(Wgs + (size_t)(k0 + half * 4) * 12);
                float wf[48];
                #pragma unroll
                for (int tchunk = 0; tchunk < 12; ++tchunk)
                    ((float4*)wf)[tchunk] = wp[tchunk];
                #pragma unroll
                for (int j2 = 0; j2 < 4; ++j2)
                    #pragma unroll
                    for (int e = 0; e < 12; ++e)
                        acc[24 + e] += xv[half * 4 + j2] * wf[j2 * 12 + e];
            }
        }
    }

    // 64-lane butterfly reduction; result broadcast to all lanes
    #pragma unroll
    for (int off = 32; off > 0; off >>= 1)
        #pragma unroll
        for (int i = 0; i < NGATE; ++i) acc[i] += __shfl_xor(acc[i], off, 64);

    float g[NGATE];
    #pragma unroll
    for (int n = 0; n < 4; ++n) {
        float z[6];
        #pragma unroll
        for (int e = 0; e < 6; ++e) z[e] = acc[n*6+e] + bg[n*6+e];
        softmaxN<6>(z);                               // first softmax
        int s0 = simdom[n*2], s1 = simdom[n*2+1];
        float z2[6];
        z2[0] = z[0]; z2[1] = z[1];
        #pragma unroll
        for (int j = 0; j < 4; ++j)
            z2[2+j] = (s0 == j || s1 == j) ? z[2+j] : -1e30f;
        softmaxN<6>(z2);                              // masked second softmax
        #pragma unroll
        for (int e = 0; e < 6; ++e) g[n*6+e] = z2[e];
    }
    {
        float z[12];
        #pragma unroll
        for (int e = 0; e < 12; ++e) z[e] = acc[24+e] + bgs[e];
        softmaxN<12>(z);
        #pragma unroll
        for (int e = 0; e < 12; ++e) g[24+e] = z[e];
    }
    if (lane < NGATE) gates[(size_t)row * NGATE + lane] = g[lane];
}

// ---------------------------------------------------------------------------
// Kernel B: fused 12-matrix GEMM + bias + ReLU + gate combine.
// Block tile 64 rows x 32 h-cols; 4 waves 2x2; BK=32; 16 K-steps.
// LDS = single 45,056 B buffer (x tiles + W tiles; gate buffer aliased onto
// dead W tiles after the K-loop) -> 3 blocks/CU. XOR-swizzled 16B k-chunks.
// ---------------------------------------------------------------------------
__global__ __launch_bounds__(256, 3) void k_main(
    const unsigned short* __restrict__ xbf,   // (5,B,512), ws base
    const float* __restrict__ gates,          // (B,36)
    const float* __restrict__ bspec,          // (4,2,256)
    const float* __restrict__ bsh,            // (4,256)
    float* __restrict__ out)                  // (5,B,256)
{
    // shorts: x tiles [5][64][32] = 10240, W tiles [12][32][32] = 12288
    __shared__ unsigned short lbuf[10240 + 12288];          // 45,056 B
    unsigned short* lw = lbuf + 10240;
    float* lg = (float*)(lbuf + 10240);                     // alias (post-K-loop)

    const int tid  = threadIdx.x;
    const int wave = tid >> 6;
    const int lane = tid & 63;
    const int row0 = blockIdx.x * 64;
    const int h0   = blockIdx.y * 32;
    const unsigned WT_OFF = 41943040u;        // WT short-offset from xbf in ws

    // --- staging: 44 slots (20 x-quarters + 24 W-halves), 11 per wave.
    unsigned goff[11];      // short offsets from xbf
    unsigned loff[11];      // short offsets from lbuf (wave-uniform)
    #pragma unroll
    for (int i = 0; i < 11; ++i) {
        int s = wave * 11 + i;
        if (s < 20) {
            int m = s >> 2, q = s & 3;
            int r  = q * 16 + (lane >> 2);               // row in 64-row tile
            int cg = (lane & 3) ^ ((r >> 1) & 3);        // swizzled global k-chunk
            goff[i] = (unsigned)((m * BB + row0 + r) * DIN + cg * 8);
            loff[i] = (unsigned)__builtin_amdgcn_readfirstlane(m * 2048 + q * 512);
        } else {
            int s2 = s - 20;
            int mat = s2 >> 1, half = s2 & 1;
            int r  = half * 16 + (lane >> 2);            // h-row in 32-row tile
            int cg = (lane & 3) ^ ((r >> 1) & 3);
            goff[i] = WT_OFF + (unsigned)(mat * (HDIM * DIN) + (h0 + r) * DIN + cg * 8);
            loff[i] = (unsigned)__builtin_amdgcn_readfirstlane(10240 + mat * 1024 + half * 512);
        }
    }

    f32x4 acc[NMAT][2];
    #pragma unroll
    for (int mat = 0; mat < NMAT; ++mat)
        #pragma unroll
        for (int mp = 0; mp < 2; ++mp)
            acc[mat][mp] = (f32x4){0.f, 0.f, 0.f, 0.f};

    const int wm = wave >> 1, wn = wave & 1;
    const int mrow0 = wm * 32;
    const int col   = wn * 16 + (lane & 15);   // B-frag h within tile
    const int arow  = lane & 15;               // A-frag row within 16
    const int quad  = lane >> 4;               // k-chunk index for frags

    // swizzle column depends only on bits 1-2 of the sub-row -> single base reg
    const int a_base = (mrow0 + arow) * 32 + (quad ^ ((arow >> 1) & 3)) * 8;
    const int b_base = 10240 + col * 32 + (quad ^ ((lane >> 1) & 3)) * 8;

    for (int ks = 0; ks < 16; ++ks) {
        __syncthreads();                       // previous tile fully consumed
        #pragma unroll
        for (int i = 0; i < 11; ++i) {
            async16(lbuf + loff[i], xbf + goff[i]);
            goff[i] += 32;                     // advance K by 32 elements
        }
        __syncthreads();                       // staging drained

        #pragma unroll
        for (int m = 0; m < 5; ++m) {
            bf16x8 a0 = *(const bf16x8*)(lbuf + a_base + m * 2048);
            bf16x8 a1 = *(const bf16x8*)(lbuf + a_base + m * 2048 + 512);
            if (m < 4) {
                #pragma unroll
                for (int e = 0; e < 2; ++e) {
                    int mat = 2 * m + e;
                    bf16x8 bv = *(const bf16x8*)(lbuf + b_base + mat * 1024);
                    acc[mat][0] = __builtin_amdgcn_mfma_f32_16x16x32_bf16(a0, bv, acc[mat][0], 0, 0, 0);
                    acc[mat][1] = __builtin_amdgcn_mfma_f32_16x16x32_bf16(a1, bv, acc[mat][1], 0, 0, 0);
                }
            } else {
                #pragma unroll
                for (int e = 0; e < 4; ++e) {
                    int mat = 8 + e;
                    bf16x8 bv = *(const bf16x8*)(lbuf + b_base + mat * 1024);
                    acc[mat][0] = __builtin_amdgcn_mfma_f32_16x16x32_bf16(a0, bv, acc[mat][0], 0, 0, 0);
                    acc[mat][1] = __builtin_amdgcn_mfma_f32_16x16x32_bf16(a1, bv, acc[mat][1], 0, 0, 0);
                }
            }
        }
    }

    // --- epilogue: gates into (dead) W-tile LDS, bias+ReLU, combine, store --
    __syncthreads();                           // all waves done reading lw
    for (int i = tid; i < 64 * NGATE; i += 256)
        lg[i] = gates[(size_t)(row0 + i / NGATE) * NGATE + (i % NGATE)];
    __syncthreads();

    const int h = h0 + col;
    float bias[NMAT];
    #pragma unroll
    for (int mat = 0; mat < 8; ++mat) bias[mat] = bspec[mat * HDIM + h];
    #pragma unroll
    for (int e = 0; e < 4; ++e)       bias[8+e] = bsh[e * HDIM + h];

    #pragma unroll
    for (int mp = 0; mp < 2; ++mp) {
        #pragma unroll
        for (int reg = 0; reg < 4; ++reg) {
            int rl = mrow0 + mp * 16 + quad * 4 + reg;   // C/D: row=(lane>>4)*4+reg
            float s[NMAT];
            #pragma unroll
            for (int mat = 0; mat < NMAT; ++mat)
                s[mat] = fmaxf(acc[mat][mp][reg] + bias[mat], 0.f);
            const float* g = lg + rl * NGATE;
            float o4 = 0.f;
            #pragma unroll
            for (int j = 0; j < 8; ++j) o4 += g[24 + j] * s[j];
            #pragma unroll
            for (int e = 0; e < 4; ++e) o4 += g[32 + e] * s[8 + e];
            size_t rowg = (size_t)(row0 + rl);
            #pragma unroll
            for (int n = 0; n < 4; ++n) {
                const float* gn = g + n * 6;
                float on = gn[0]*s[n*2] + gn[1]*s[n*2+1]
                         + gn[2]*s[8] + gn[3]*s[9] + gn[4]*s[10] + gn[5]*s[11];
                out[((size_t)n * BB + rowg) * HDIM + h] = on;
            }
            out[((size_t)4 * BB + rowg) * HDIM + h] = o4;
        }
    }
}

// ---------------------------------------------------------------------------
extern "C" void kernel_launch(void* const* d_in, const int* in_sizes, int n_in,
                              void* d_out, int out_size, void* d_ws, size_t ws_size,
                              hipStream_t stream) {
    const float* x      = (const float*)d_in[0];
    const int*   simdom = (const int*)  d_in[1];
    const float* Wspec  = (const float*)d_in[2];
    const float* bspec  = (const float*)d_in[3];
    const float* Wsh    = (const float*)d_in[4];
    const float* bsh    = (const float*)d_in[5];
    const float* Wg     = (const float*)d_in[6];
    const float* bg     = (const float*)d_in[7];
    const float* Wgs    = (const float*)d_in[8];
    const float* bgs    = (const float*)d_in[9];
    float* out = (float*)d_out;

    uint8_t* ws = (uint8_t*)d_ws;
    unsigned short* xbf = (unsigned short*)ws;                       // 83,886,080 B
    unsigned short* WT  = (unsigned short*)(ws + 83886080ull);       //  3,145,728 B
    float*          gts = (float*)(ws + 83886080ull + 3145728ull);   //  2,359,296 B
    (void)WT;

    k_wconv<<<dim3(8, 4, 12), 256, 0, stream>>>(Wspec, Wsh, (unsigned short*)(ws + 83886080ull));
    k_prep<<<BB / 4, 256, 0, stream>>>(x, simdom, Wg, bg, Wgs, bgs, xbf, gts);
    k_main<<<dim3(BB / 64, HDIM / 32), 256, 0, stream>>>(xbf, gts, bspec, bsh, out);
}

// Round 3
// 454.030 us; speedup vs baseline: 1.3208x; 1.3208x over previous
//
#include <hip/hip_runtime.h>
#include <cstdint>
#include <cstddef>

#define D_NUM 4
#define N_ES  2
#define N_SH  4
#define DIN   512
#define HDIM  256
#define BB    16384
#define MHALF 8192
#define NMAT  12
#define NGATE 36

typedef __bf16 bf16x8 __attribute__((ext_vector_type(8)));
typedef float  f32x4  __attribute__((ext_vector_type(4)));

__device__ __forceinline__ unsigned short f2bf(float f) {
    union { float f; unsigned u; } v; v.f = f;
    unsigned u = v.u;
    unsigned r = (u + 0x7FFFu + ((u >> 16) & 1u)) >> 16;   // RNE
    return (unsigned short)r;
}
__device__ __forceinline__ float bf2f(unsigned short u) {
    union { unsigned u; float f; } v; v.u = ((unsigned)u) << 16; return v.f;
}
__device__ __forceinline__ void async16(void* l, const void* g) {
    __builtin_amdgcn_global_load_lds(
        (const __attribute__((address_space(1))) void*)g,
        (__attribute__((address_space(3))) void*)l,
        16, 0, 0);
}

// ---------------------------------------------------------------------------
// k_wconv: W -> bf16 WT[mat][h][k] via LDS transpose tiles (coalesced).
// ---------------------------------------------------------------------------
__global__ __launch_bounds__(256) void k_wconv(
    const float* __restrict__ Wspec,   // (8,512,256) flattened (mat,k,h)
    const float* __restrict__ Wsh,     // (4,512,256)
    unsigned short* __restrict__ WT)   // (12,256,512)
{
    __shared__ unsigned short t[64][65];
    const int mat = blockIdx.z;
    const int k0  = blockIdx.x * 64;
    const int h0  = blockIdx.y * 64;
    const float* src = (mat < 8) ? (Wspec + (size_t)mat * DIN * HDIM)
                                 : (Wsh   + (size_t)(mat - 8) * DIN * HDIM);
    #pragma unroll
    for (int i = 0; i < 16; ++i) {
        int idx = i * 256 + threadIdx.x;
        int r = idx >> 6, c = idx & 63;
        t[r][c] = f2bf(src[(size_t)(k0 + r) * HDIM + h0 + c]);
    }
    __syncthreads();
    #pragma unroll
    for (int i = 0; i < 16; ++i) {
        int idx = i * 256 + threadIdx.x;
        int r = idx >> 6, c = idx & 63;
        WT[(size_t)mat * HDIM * DIN + (size_t)(h0 + r) * DIN + k0 + c] = t[c][r];
    }
}

// ---------------------------------------------------------------------------
// k_gwt: transpose gate weights. WgT[n][e][k] = Wg[n][k][e]; WgsT[e][k].
// ---------------------------------------------------------------------------
__global__ __launch_bounds__(256) void k_gwt(
    const float* __restrict__ Wg,      // (4,512,6)
    const float* __restrict__ Wgs,     // (512,12)
    float* __restrict__ WgT,           // (4,6,512)
    float* __restrict__ WgsT)          // (12,512)
{
    int i = blockIdx.x * 256 + threadIdx.x;
    if (i < 4 * 6 * 512) {
        int n = i / 3072, rem = i % 3072;
        int e = rem >> 9, k = rem & 511;
        WgT[i] = Wg[((size_t)n * DIN + k) * 6 + e];
    }
    if (i < 12 * 512) {
        int e = i >> 9, k = i & 511;
        WgsT[i] = Wgs[(size_t)k * 12 + e];
    }
}

// ---------------------------------------------------------------------------
// k_prep: x f32 -> bf16 + gates. One wave per row. Per-plane transient
// accumulators + transposed gate weights -> no arrays, no scratch.
// ---------------------------------------------------------------------------
__global__ __launch_bounds__(256) void k_prep(
    const float* __restrict__ x,        // (5,B,512)
    const int*   __restrict__ simdom,   // (4,2)
    const float* __restrict__ WgT,      // (4,6,512)
    const float* __restrict__ bg,       // (4,6)
    const float* __restrict__ WgsT,     // (12,512)
    const float* __restrict__ bgs,      // (12)
    unsigned short* __restrict__ xbf,   // (5,B,512)
    float* __restrict__ gates)          // (B,36)
{
    __shared__ float lgate[4][40];
    const int wave = threadIdx.x >> 6;
    const int lane = threadIdx.x & 63;
    const int row  = blockIdx.x * 4 + wave;
    const int k0   = lane * 8;

    #pragma unroll
    for (int m = 0; m < 5; ++m) {
        const float* xp = x + ((size_t)m * BB + row) * DIN + k0;
        float4 a = ((const float4*)xp)[0], b = ((const float4*)xp)[1];
        union { unsigned short us[8]; uint4 v; } pk;
        pk.us[0]=f2bf(a.x); pk.us[1]=f2bf(a.y); pk.us[2]=f2bf(a.z); pk.us[3]=f2bf(a.w);
        pk.us[4]=f2bf(b.x); pk.us[5]=f2bf(b.y); pk.us[6]=f2bf(b.z); pk.us[7]=f2bf(b.w);
        *(uint4*)(xbf + ((size_t)m * BB + row) * DIN + k0) = pk.v;

        if (m < 4) {
            float z[6];
            #pragma unroll
            for (int e = 0; e < 6; ++e) {
                const float* wp = WgT + ((size_t)(m * 6 + e)) * DIN + k0;
                float4 wa = ((const float4*)wp)[0], wb = ((const float4*)wp)[1];
                z[e] = a.x*wa.x + a.y*wa.y + a.z*wa.z + a.w*wa.w
                     + b.x*wb.x + b.y*wb.y + b.z*wb.z + b.w*wb.w;
            }
            #pragma unroll
            for (int off = 32; off > 0; off >>= 1)
                #pragma unroll
                for (int e = 0; e < 6; ++e) z[e] += __shfl_xor(z[e], off, 64);
            // softmax 1
            #pragma unroll
            for (int e = 0; e < 6; ++e) z[e] += bg[m * 6 + e];
            float mx = z[0];
            #pragma unroll
            for (int e = 1; e < 6; ++e) mx = fmaxf(mx, z[e]);
            float sum = 0.f;
            #pragma unroll
            for (int e = 0; e < 6; ++e) { z[e] = __expf(z[e] - mx); sum += z[e]; }
            float inv = 1.f / sum;
            #pragma unroll
            for (int e = 0; e < 6; ++e) z[e] *= inv;
            // mask + softmax 2 (shared slots only kept if domain member)
            int s0 = simdom[m * 2], s1 = simdom[m * 2 + 1];
            float z2[6];
            z2[0] = z[0]; z2[1] = z[1];
            #pragma unroll
            for (int j = 0; j < 4; ++j)
                z2[2 + j] = (s0 == j || s1 == j) ? z[2 + j] : 0.f;   // exp(-inf)=0
            // second softmax on probs+mask == renormalize exp(z)/... careful:
            // reference does softmax(softmax1_out + mask). Do it exactly:
            {
                float w[6];
                w[0] = z[0]; w[1] = z[1];
                #pragma unroll
                for (int j = 0; j < 4; ++j)
                    w[2 + j] = (s0 == j || s1 == j) ? z[2 + j] : -1e30f;
                float mx2 = w[0];
                #pragma unroll
                for (int e = 1; e < 6; ++e) mx2 = fmaxf(mx2, w[e]);
                float sm = 0.f;
                #pragma unroll
                for (int e = 0; e < 6; ++e) { w[e] = __expf(w[e] - mx2); sm += w[e]; }
                float iv = 1.f / sm;
                if (lane == 0) {
                    #pragma unroll
                    for (int e = 0; e < 6; ++e) lgate[wave][m * 6 + e] = w[e] * iv;
                }
            }
        } else {
            float z[12];
            #pragma unroll
            for (int e = 0; e < 12; ++e) {
                const float* wp = WgsT + (size_t)e * DIN + k0;
                float4 wa = ((const float4*)wp)[0], wb = ((const float4*)wp)[1];
                z[e] = a.x*wa.x + a.y*wa.y + a.z*wa.z + a.w*wa.w
                     + b.x*wb.x + b.y*wb.y + b.z*wb.z + b.w*wb.w;
            }
            #pragma unroll
            for (int off = 32; off > 0; off >>= 1)
                #pragma unroll
                for (int e = 0; e < 12; ++e) z[e] += __shfl_xor(z[e], off, 64);
            #pragma unroll
            for (int e = 0; e < 12; ++e) z[e] += bgs[e];
            float mx = z[0];
            #pragma unroll
            for (int e = 1; e < 12; ++e) mx = fmaxf(mx, z[e]);
            float sum = 0.f;
            #pragma unroll
            for (int e = 0; e < 12; ++e) { z[e] = __expf(z[e] - mx); sum += z[e]; }
            float inv = 1.f / sum;
            if (lane == 0) {
                #pragma unroll
                for (int e = 0; e < 12; ++e) lgate[wave][24 + e] = z[e] * inv;
            }
        }
    }
    if (lane < NGATE) gates[(size_t)row * NGATE + lane] = lgate[wave][lane];
}

// ---------------------------------------------------------------------------
// k_gemm: batched 12-mat GEMM, m97 structure. Tile 128x128, BK=64, 4 waves.
// grid = (MHALF/128, 24); mat = y>>1, h-half = (y&1)*128. Writes bf16
// S[mat][lrow][h] with bias+ReLU. 16B chunks XOR-swizzled by (row&7).
// ---------------------------------------------------------------------------
__global__ __launch_bounds__(256) void k_gemm(
    const unsigned short* __restrict__ xbf,   // (5,B,512)
    const unsigned short* __restrict__ WT,    // (12,256,512)
    const float* __restrict__ bspec,          // (8,256)
    const float* __restrict__ bsh,            // (4,256)
    unsigned short* __restrict__ S,           // (12,MHALF,256)
    int row_base)
{
    __shared__ unsigned short lbuf[16384];    // A [0,8192), B [8192,16384) shorts

    const int tid  = threadIdx.x;
    const int wave = tid >> 6;
    const int lane = tid & 63;
    const int mat  = blockIdx.y >> 1;
    const int hh0  = (blockIdx.y & 1) * 128;
    const int plane = (mat < 8) ? (mat >> 1) : 4;
    const int lrow0 = blockIdx.x * 128;

    const unsigned short* Abase = xbf + ((size_t)plane * BB + row_base + lrow0) * DIN;
    const unsigned short* Bbase = WT + (size_t)mat * HDIM * DIN + (size_t)hh0 * DIN;

    // staging: waves 0,1 -> A rows 0..127; waves 2,3 -> B rows 0..127
    const unsigned short* gb = (wave < 2) ? Abase : Bbase;
    unsigned goff[8];
    unsigned loff[8];
    {
        int cg = (lane & 7) ^ ((lane >> 3) & 7);     // swizzled source chunk
        #pragma unroll
        for (int i = 0; i < 8; ++i) {
            int slot = wave * 8 + i;
            int r = (slot & 15) * 8 + (lane >> 3);
            goff[i] = (unsigned)(r * DIN + cg * 8);
            loff[i] = (unsigned)(slot * 512);        // shorts, wave-uniform
        }
    }

    f32x4 acc[4][4];
    #pragma unroll
    for (int t = 0; t < 4; ++t)
        #pragma unroll
        for (int u = 0; u < 4; ++u)
            acc[t][u] = (f32x4){0.f, 0.f, 0.f, 0.f};

    const int wm = wave >> 1, wn = wave & 1;
    const int arow = lane & 15, quad = lane >> 4;
    int aofs[4], bofs[4];
    #pragma unroll
    for (int t = 0; t < 4; ++t) {
        int r = wm * 64 + t * 16 + arow;
        aofs[t] = r * 64 + (quad ^ (r & 7)) * 8;
    }
    #pragma unroll
    for (int u = 0; u < 4; ++u) {
        int r = wn * 64 + u * 16 + arow;
        bofs[u] = 8192 + r * 64 + (quad ^ (r & 7)) * 8;
    }

    for (int ks = 0; ks < 8; ++ks) {
        __syncthreads();
        #pragma unroll
        for (int i = 0; i < 8; ++i) {
            async16(lbuf + loff[i], gb + goff[i]);
            goff[i] += 64;                            // next BK window
        }
        __syncthreads();

        #pragma unroll
        for (int s2 = 0; s2 < 2; ++s2) {
            const int sx = s2 * 32;                   // flips phys-chunk bit 2
            bf16x8 af[4], bv[4];
            #pragma unroll
            for (int t = 0; t < 4; ++t) af[t] = *(const bf16x8*)(lbuf + (aofs[t] ^ sx));
            #pragma unroll
            for (int u = 0; u < 4; ++u) bv[u] = *(const bf16x8*)(lbuf + (bofs[u] ^ sx));
            #pragma unroll
            for (int t = 0; t < 4; ++t)
                #pragma unroll
                for (int u = 0; u < 4; ++u)
                    acc[t][u] = __builtin_amdgcn_mfma_f32_16x16x32_bf16(af[t], bv[u], acc[t][u], 0, 0, 0);
        }
    }

    // epilogue: bias + ReLU + bf16 store
    #pragma unroll
    for (int u = 0; u < 4; ++u) {
        const int h = hh0 + wn * 64 + u * 16 + arow;
        const float bias = (mat < 8) ? bspec[mat * HDIM + h] : bsh[(mat - 8) * HDIM + h];
        #pragma unroll
        for (int t = 0; t < 4; ++t) {
            #pragma unroll
            for (int reg = 0; reg < 4; ++reg) {
                int lr = lrow0 + wm * 64 + t * 16 + quad * 4 + reg;
                float v = fmaxf(acc[t][u][reg] + bias, 0.f);
                S[((size_t)mat * MHALF + lr) * HDIM + h] = f2bf(v);
            }
        }
    }
}

// ---------------------------------------------------------------------------
// k_comb: out[n][row][h] from S + gates. Streaming. 4 rows per block.
// ---------------------------------------------------------------------------
__global__ __launch_bounds__(256) void k_comb(
    const unsigned short* __restrict__ S,     // (12,MHALF,256)
    const float* __restrict__ gates,          // (B,36)
    float* __restrict__ out,                  // (5,B,256)
    int row_base)
{
    const int h = threadIdx.x;
    const int r0 = blockIdx.x * 4;
    #pragma unroll
    for (int rr = 0; rr < 4; ++rr) {
        const int lr = r0 + rr;
        const int grow = row_base + lr;
        const float* g = gates + (size_t)grow * NGATE;
        float s[NMAT];
        #pragma unroll
        for (int mat = 0; mat < NMAT; ++mat)
            s[mat] = bf2f(S[((size_t)mat * MHALF + lr) * HDIM + h]);
        float o4 = 0.f;
        #pragma unroll
        for (int j = 0; j < 8; ++j) o4 += g[24 + j] * s[j];
        #pragma unroll
        for (int e = 0; e < 4; ++e) o4 += g[32 + e] * s[8 + e];
        #pragma unroll
        for (int n = 0; n < 4; ++n) {
            float on = g[n*6+0]*s[n*2] + g[n*6+1]*s[n*2+1]
                     + g[n*6+2]*s[8] + g[n*6+3]*s[9] + g[n*6+4]*s[10] + g[n*6+5]*s[11];
            out[((size_t)n * BB + grow) * HDIM + h] = on;
        }
        out[((size_t)4 * BB + grow) * HDIM + h] = o4;
    }
}

// ---------------------------------------------------------------------------
extern "C" void kernel_launch(void* const* d_in, const int* in_sizes, int n_in,
                              void* d_out, int out_size, void* d_ws, size_t ws_size,
                              hipStream_t stream) {
    const float* x      = (const float*)d_in[0];
    const int*   simdom = (const int*)  d_in[1];
    const float* Wspec  = (const float*)d_in[2];
    const float* bspec  = (const float*)d_in[3];
    const float* Wsh    = (const float*)d_in[4];
    const float* bsh    = (const float*)d_in[5];
    const float* Wg     = (const float*)d_in[6];
    const float* bg     = (const float*)d_in[7];
    const float* Wgs    = (const float*)d_in[8];
    const float* bgs    = (const float*)d_in[9];
    float* out = (float*)d_out;

    uint8_t* ws = (uint8_t*)d_ws;
    unsigned short* xbf  = (unsigned short*)(ws);                      // 83,886,080
    unsigned short* WT   = (unsigned short*)(ws + 83886080ull);        //  3,145,728
    float*          gts  = (float*)(ws + 87031808ull);                 //  2,359,296
    float*          WgT  = (float*)(ws + 89391104ull);                 //     49,152
    float*          WgsT = (float*)(ws + 89440256ull);                 //     24,576
    unsigned short* S    = (unsigned short*)(ws + 89464832ull);        // 50,331,648 (ends ~139.8 MB)

    k_wconv<<<dim3(8, 4, 12), 256, 0, stream>>>(Wspec, Wsh, WT);
    k_gwt<<<48, 256, 0, stream>>>(Wg, Wgs, WgT, WgsT);
    k_prep<<<BB / 4, 256, 0, stream>>>(x, simdom, WgT, bg, WgsT, bgs, xbf, gts);
    for (int half = 0; half < 2; ++half) {
        int row_base = half * MHALF;
        k_gemm<<<dim3(MHALF / 128, 24), 256, 0, stream>>>(xbf, WT, bspec, bsh, S, row_base);
        k_comb<<<MHALF / 4, 256, 0, stream>>>(S, gts, out, row_base);
    }
}